// Round 3
// baseline (2278.027 us; speedup 1.0000x reference)
//
#include <hip/hip_runtime.h>
#include <cstdint>
#include <cstddef>

// Problem constants
#define NUM_C 4096
#define BB 32
#define TT 512
#define DD 128
#define MM 50

using ull = unsigned long long;

__device__ __forceinline__ float sigmoidf_(float x){ return 1.0f/(1.0f + expf(-x)); }

__device__ __forceinline__ unsigned short f2bf_(float x){
  union { float f; unsigned u; } v; v.f = x;
  unsigned r = v.u + 0x7FFFu + ((v.u >> 16) & 1u);   // round-to-nearest-even
  return (unsigned short)(r >> 16);
}
__device__ __forceinline__ float bf2f_(unsigned short h){
  union { unsigned u; float f; } v; v.u = ((unsigned)h) << 16;
  return v.f;
}

// ---------------------------------------------------------------------------
// Kernel A: parallel precompute (unchanged from R1).
// ---------------------------------------------------------------------------
__global__ __launch_bounds__(256) void kPre(
    const int* __restrict__ q, const int* __restrict__ r,
    const float* __restrict__ k_emb, const float* __restrict__ Mk,
    const float* __restrict__ f_W, const float* __restrict__ f_b,
    const float* __restrict__ a_W, const float* __restrict__ a_b,
    float* __restrict__ wAll, ull* __restrict__ keyLo, ull* __restrict__ keyHi,
    float* __restrict__ fpre, float* __restrict__ ypre)
{
  const int b = blockIdx.y, t0 = blockIdx.x * 32, tid = threadIdx.x;
  __shared__ __align__(16) float sK[32*129];
  __shared__ int sQ[32];
  __shared__ int sR[32];
  __shared__ union UU {
    struct { float sMk[MM*129]; double sZ[32*MM]; } p2;
    float sW2[128*65];
  } u;

  if (tid < 32){ sQ[tid] = q[b*TT + t0 + tid]; sR[tid] = r[b*TT + t0 + tid]; }
  __syncthreads();
  for (int i = tid; i < 32*128; i += 256){
    int tl = i >> 7, j = i & 127;
    sK[tl*129 + j] = k_emb[(size_t)sQ[tl]*DD + j];
  }
  for (int i = tid; i < MM*128; i += 256){
    int m = i >> 7, j = i & 127;
    u.p2.sMk[m*129 + j] = Mk[i];
  }
  __syncthreads();

  for (int idx = tid; idx < 32*MM; idx += 256){
    int tl = idx / MM, m = idx - tl*MM;
    double z = 0.0;
    for (int j = 0; j < DD; j++)
      z += (double)sK[tl*129 + j] * (double)u.p2.sMk[m*129 + j];
    u.p2.sZ[tl*MM + m] = z;
  }
  __syncthreads();

  {
    int tl = tid >> 3, l8 = tid & 7;
    double zmax = -1e300;
    for (int m = l8; m < MM; m += 8) zmax = fmax(zmax, u.p2.sZ[tl*MM + m]);
    for (int s = 1; s < 8; s <<= 1) zmax = fmax(zmax, __shfl_xor(zmax, s));
    double se = 0.0;
    for (int m = l8; m < MM; m += 8){
      double e = exp(u.p2.sZ[tl*MM + m] - zmax);
      u.p2.sZ[tl*MM + m] = e;
      se += e;
    }
    for (int s = 1; s < 8; s <<= 1) se += __shfl_xor(se, s);
    double inv = 1.0 / se;
    ull klo = 0, khi = 0;
    for (int m = l8; m < MM; m += 8){
      double w = u.p2.sZ[tl*MM + m] * inv;
      wAll[((size_t)(b*TT + t0 + tl))*MM + m] = (float)w;
      double tw = fmin((w - 0.075)/(0.088 - 0.075), (1.0 - w)/(1.0 - 0.088));
      tw = fmax(tw, 0.0);
      ull iv = (tw >= 0.6) ? 2ull : ((tw >= 0.1) ? 1ull : 0ull);
      if (m < 32) klo |= iv << (2*m); else khi |= iv << (2*(m-32));
    }
    for (int s = 1; s < 8; s <<= 1){ klo |= __shfl_xor(klo, s); khi |= __shfl_xor(khi, s); }
    if (l8 == 0){ keyLo[b*TT + t0 + tl] = klo; keyHi[b*TT + t0 + tl] = khi; }
  }

  {
    const int dq = tid & 31, tq = tid >> 5;
    float acc[4][4];
    #pragma unroll
    for (int a = 0; a < 4; a++){ acc[a][0]=0.f; acc[a][1]=0.f; acc[a][2]=0.f; acc[a][3]=0.f; }
    for (int jh = 0; jh < 2; jh++){
      __syncthreads();
      for (int i = tid; i < 128*64; i += 256){
        int dd = i >> 6, jj = i & 63;
        u.sW2[dd*65 + jj] = f_W[dd*256 + 128 + jh*64 + jj];
      }
      __syncthreads();
      for (int jj = 0; jj < 64; jj++){
        float kv[4], wv[4];
        #pragma unroll
        for (int a = 0; a < 4; a++) kv[a] = sK[(tq*4 + a)*129 + jh*64 + jj];
        #pragma unroll
        for (int c = 0; c < 4; c++) wv[c] = u.sW2[(dq*4 + c)*65 + jj];
        #pragma unroll
        for (int a = 0; a < 4; a++){
          acc[a][0] += kv[a]*wv[0]; acc[a][1] += kv[a]*wv[1];
          acc[a][2] += kv[a]*wv[2]; acc[a][3] += kv[a]*wv[3];
        }
      }
    }
    #pragma unroll
    for (int a = 0; a < 4; a++){
      int tl = tq*4 + a;
      #pragma unroll
      for (int c = 0; c < 4; c++){
        int d = dq*4 + c;
        fpre[((size_t)(b*TT + t0 + tl))*DD + d] = acc[a][c] + f_b[d];
      }
    }
  }

  for (int i = tid; i < 32*DD; i += 256){
    int tl = i >> 7, d = i & 127;
    ypre[((size_t)(b*TT + t0 + tl))*DD + d] =
        a_W[(size_t)d*(NUM_C + DD) + sQ[tl]] * (float)sR[tl] + a_b[d];
  }
}

// ---------------------------------------------------------------------------
// Kernel A2: exact match search (unchanged).
// ---------------------------------------------------------------------------
__global__ __launch_bounds__(512) void kMatch(
    const ull* __restrict__ keyLo, const ull* __restrict__ keyHi, int* __restrict__ prevA)
{
  const int b = blockIdx.x, i = threadIdx.x;
  __shared__ ull slo[TT];
  __shared__ ull shi[TT];
  slo[i] = keyLo[b*TT + i];
  shi[i] = keyHi[b*TT + i];
  __syncthreads();
  const ull mylo = slo[i], myhi = shi[i];
  int found = -1;
  for (int j = i - 1; j >= 0; j--){
    if (slo[j] == mylo && shi[j] == myhi){ found = j; break; }
  }
  prevA[b*TT + i] = found;
}

// ---------------------------------------------------------------------------
// Kernel B (R2): memory recurrence with ZERO per-step global traffic.
// wAll/fpre/ypre staged in LDS per 8-step chunk; fAll buffered in LDS and
// flushed per chunk. Mv + 4 weight matrices in registers (as R1).
// Per step: 3 barriers, no vmcnt content to drain except once per chunk.
// ---------------------------------------------------------------------------
__global__ __launch_bounds__(512, 2) void kMem(
    const float* __restrict__ wAll, const float* __restrict__ fpre, const float* __restrict__ ypre,
    const float* __restrict__ f_W, const float* __restrict__ a_W,
    const float* __restrict__ e_W, const float* __restrict__ e_b,
    const float* __restrict__ add_W, const float* __restrict__ add_b,
    const float* __restrict__ Mv0, float* __restrict__ fAll)
{
  const int b = blockIdx.x, tid = threadIdx.x;
  const int w = tid >> 6, l = tid & 63;
  const int d = w*16 + (l & 15);
  const int kc = l >> 4;                 // 0..3
  const int m0 = kc*13;                  // m-chunk base (13,13,13,11)
  const int slice = w >> 1;
  const int dIn = (w & 1)*16 + (l & 15);

  // register-resident state & weights (vectorized one-time loads)
  float mv[13];
  #pragma unroll
  for (int i = 0; i < 13; i++){
    int m = m0 + i;
    mv[i] = (m < MM) ? Mv0[(size_t)m*DD + d] : 0.f;
  }
  float wf[32], wa[32], we[32], wd[32];
  {
    const float4* p;
    p = reinterpret_cast<const float4*>(&f_W[d*256 + kc*32]);
    #pragma unroll
    for (int i = 0; i < 8; i++){ float4 v = p[i]; wf[4*i]=v.x; wf[4*i+1]=v.y; wf[4*i+2]=v.z; wf[4*i+3]=v.w; }
    p = reinterpret_cast<const float4*>(&a_W[(size_t)d*(NUM_C + DD) + NUM_C + kc*32]);
    #pragma unroll
    for (int i = 0; i < 8; i++){ float4 v = p[i]; wa[4*i]=v.x; wa[4*i+1]=v.y; wa[4*i+2]=v.z; wa[4*i+3]=v.w; }
    p = reinterpret_cast<const float4*>(&e_W[d*DD + kc*32]);
    #pragma unroll
    for (int i = 0; i < 8; i++){ float4 v = p[i]; we[4*i]=v.x; we[4*i+1]=v.y; we[4*i+2]=v.z; we[4*i+3]=v.w; }
    p = reinterpret_cast<const float4*>(&add_W[d*DD + kc*32]);
    #pragma unroll
    for (int i = 0; i < 8; i++){ float4 v = p[i]; wd[4*i]=v.x; wd[4*i+1]=v.y; wd[4*i+2]=v.z; wd[4*i+3]=v.w; }
  }
  const float ebv = e_b[d], adbv = add_b[d];

  __shared__ __align__(16) float bufR[144];
  __shared__ __align__(16) float bufF[144];
  __shared__ __align__(16) float bufY[144];
  __shared__ float sW8[8*52];                 // wAll chunk
  __shared__ __align__(16) float sF8[8*128];  // fpre chunk
  __shared__ __align__(16) float sY8[8*128];  // ypre chunk
  __shared__ __align__(16) float fO8[8*128];  // fAll out-buffer

  const size_t base = (size_t)b*TT;

  for (int t = 0; t < TT; t++){
    const int tc = t & 7;
    if (tc == 0){
      // flush previous chunk's fO8 (steps t-8 .. t-1)
      if (t){
        if (tid < 256){
          const float4* s4 = reinterpret_cast<const float4*>(fO8);
          float4 v = s4[tid];
          reinterpret_cast<float4*>(&fAll[(base + t - 8)*DD])[tid] = v;
        }
      }
      // refill staging for steps t .. t+7
      if (tid < 256){
        float4 v = reinterpret_cast<const float4*>(&fpre[(base + t)*DD])[tid];
        reinterpret_cast<float4*>(sF8)[tid] = v;
      } else {
        float4 v = reinterpret_cast<const float4*>(&ypre[(base + t)*DD])[tid - 256];
        reinterpret_cast<float4*>(sY8)[tid - 256] = v;
      }
      if (tid < 400){
        int rr = tid / MM, mm = tid - rr*MM;
        sW8[rr*52 + mm] = wAll[(base + t + rr)*MM + mm];
      }
      __syncthreads();   // R
    }

    // per-step w row into registers (LDS broadcast reads; reused in stage 5)
    float wcur[13];
    #pragma unroll
    for (int i = 0; i < 13; i++)
      wcur[i] = (m0 + i < MM) ? sW8[tc*52 + m0 + i] : 0.f;

    // ---- stage 1: read[d] = sum_m w[m]*Mv[m][d] (registers only) ----
    {
      float a0 = 0.f;
      #pragma unroll
      for (int i = 0; i < 13; i++) a0 += wcur[i]*mv[i];
      a0 += __shfl_xor(a0, 16);
      a0 += __shfl_xor(a0, 32);
      if (kc == 0) bufR[slice*36 + dIn] = a0;
    }
    __syncthreads();   // A

    // ---- stage 2: f = tanh(read @ f_Wr.T + fpre) ----
    {
      const float4* x4 = reinterpret_cast<const float4*>(&bufR[kc*36]);
      float a0=0.f,a1=0.f,a2=0.f,a3=0.f;
      #pragma unroll
      for (int i = 0; i < 8; i++){
        float4 xv = x4[i];
        a0 += xv.x*wf[4*i]; a1 += xv.y*wf[4*i+1]; a2 += xv.z*wf[4*i+2]; a3 += xv.w*wf[4*i+3];
      }
      float s = (a0+a1)+(a2+a3);
      s += __shfl_xor(s, 16);
      s += __shfl_xor(s, 32);
      float fval = tanhf(s + sF8[tc*128 + d]);
      if (kc == 0){
        bufF[slice*36 + dIn] = fval;
        fO8[tc*128 + d] = fval;
      }
    }
    __syncthreads();   // B

    // ---- stage 3: y = ypre + f @ a_Wf.T ----
    {
      const float4* x4 = reinterpret_cast<const float4*>(&bufF[kc*36]);
      float a0=0.f,a1=0.f,a2=0.f,a3=0.f;
      #pragma unroll
      for (int i = 0; i < 8; i++){
        float4 xv = x4[i];
        a0 += xv.x*wa[4*i]; a1 += xv.y*wa[4*i+1]; a2 += xv.z*wa[4*i+2]; a3 += xv.w*wa[4*i+3];
      }
      float s = (a0+a1)+(a2+a3);
      s += __shfl_xor(s, 16);
      s += __shfl_xor(s, 32);
      if (kc == 0) bufY[slice*36 + dIn] = s + sY8[tc*128 + d];
    }
    __syncthreads();   // C

    // ---- stage 4: e,a + Mv register update (no barrier) ----
    {
      const float4* x4 = reinterpret_cast<const float4*>(&bufY[kc*36]);
      float e0=0.f,e1=0.f,g0=0.f,g1=0.f;
      #pragma unroll
      for (int i = 0; i < 8; i++){
        float4 xv = x4[i];
        e0 += xv.x*we[4*i];   e1 += xv.y*we[4*i+1];
        e0 += xv.z*we[4*i+2]; e1 += xv.w*we[4*i+3];
        g0 += xv.x*wd[4*i];   g1 += xv.y*wd[4*i+1];
        g0 += xv.z*wd[4*i+2]; g1 += xv.w*wd[4*i+3];
      }
      float ep = e0 + e1, ap = g0 + g1;
      ep += __shfl_xor(ep, 16);  ep += __shfl_xor(ep, 32);
      ap += __shfl_xor(ap, 16);  ap += __shfl_xor(ap, 32);
      float e_d = sigmoidf_(ep + ebv);
      float a_d = tanhf(ap + adbv);
      #pragma unroll
      for (int i = 0; i < 13; i++){
        float wv = wcur[i];
        mv[i] = mv[i]*(1.f - wv*e_d) + wv*a_d;
      }
    }
  }

  // final flush (steps 504..511)
  __syncthreads();
  if (tid < 256){
    const float4* s4 = reinterpret_cast<const float4*>(fO8);
    float4 v = s4[tid];
    reinterpret_cast<float4*>(&fAll[(base + TT - 8)*DD])[tid] = v;
  }
}

// ---------------------------------------------------------------------------
// Kernel D: gpre GEMM (unchanged).
// ---------------------------------------------------------------------------
__global__ __launch_bounds__(256) void kGate(
    const float* __restrict__ fAll, const float* __restrict__ Wih,
    const float* __restrict__ bih, const float* __restrict__ bhh,
    float* __restrict__ gpre)
{
  const int jt = blockIdx.x;
  const int rt = blockIdx.y;
  const int tid = threadIdx.x;
  __shared__ float sW[64*129];
  __shared__ float sF[32*129];
  for (int i = tid; i < 64*128; i += 256){
    int jj = i >> 7, k = i & 127;
    sW[jj*129 + k] = Wih[(size_t)(jt*64 + jj)*128 + k];
  }
  for (int i = tid; i < 32*128; i += 256){
    int rr = i >> 7, k = i & 127;
    sF[rr*129 + k] = fAll[(size_t)(rt*32 + rr)*128 + k];
  }
  __syncthreads();
  const int jq = tid & 31, rq = tid >> 5;
  float acc[4][2];
  #pragma unroll
  for (int a = 0; a < 4; a++){ acc[a][0] = 0.f; acc[a][1] = 0.f; }
  for (int k = 0; k < 128; k++){
    float fv[4], wv[2];
    #pragma unroll
    for (int a = 0; a < 4; a++) fv[a] = sF[(rq*4 + a)*129 + k];
    wv[0] = sW[(jq*2 + 0)*129 + k];
    wv[1] = sW[(jq*2 + 1)*129 + k];
    #pragma unroll
    for (int a = 0; a < 4; a++){ acc[a][0] += fv[a]*wv[0]; acc[a][1] += fv[a]*wv[1]; }
  }
  #pragma unroll
  for (int a = 0; a < 4; a++){
    int rowi = rt*32 + rq*4 + a;
    #pragma unroll
    for (int c = 0; c < 2; c++){
      int j = jt*64 + jq*2 + c;
      gpre[(size_t)rowi*512 + j] = acc[a][c] + bih[j] + bhh[j];
    }
  }
}

// ---------------------------------------------------------------------------
// Kernel C (R2): LSTM. Per-step globals evicted:
//  - prevA -> LDS once; gpre -> LDS chunks of 8 steps; H history -> LDS bf16
//    (128 KB); only C history stays global fp32 (same-thread write/read,
//    L2-resident, prefetched one step ahead).
// ---------------------------------------------------------------------------
__global__ __launch_bounds__(512, 1) void kLstm(
    const float* __restrict__ gpre, const int* __restrict__ prevA,
    const float* __restrict__ Whh, const float* __restrict__ p_W, const float* __restrict__ p_b,
    float* __restrict__ Ch, float* __restrict__ out)
{
  const int b = blockIdx.x, j = threadIdx.x;
  float whh[128];
  {
    const float4* W4 = reinterpret_cast<const float4*>(&Whh[(size_t)j*128]);
    #pragma unroll
    for (int i = 0; i < 32; i++){
      float4 v = W4[i];
      whh[4*i] = v.x; whh[4*i+1] = v.y; whh[4*i+2] = v.z; whh[4*i+3] = v.w;
    }
  }
  __shared__ unsigned short Hh16[TT*DD];          // 128 KB bf16 h history
  __shared__ __align__(16) float gbuf[8*512];     // 16 KB gpre chunk
  __shared__ int spv[TT];                         // 2 KB prevA
  __shared__ __align__(16) float xh[DD];
  __shared__ float sg[512];
  __shared__ float sh[DD];
  __shared__ float sc[DD];
  __shared__ float pred[DD];

  const size_t base = (size_t)b*TT;
  spv[j] = prevA[base + j];
  if (j < DD){ sh[j] = 0.f; sc[j] = 0.f; }
  const float pwv = (j < DD) ? p_W[j] : 0.f;
  const float pbv = p_b[0];
  float preC = 0.f;     // prefetched skip-c for current step
  __syncthreads();

  for (int t = 0; t < TT; t++){
    const int tc = t & 7;
    if (tc == 0){
      const float4* gp = reinterpret_cast<const float4*>(&gpre[(base + t)*512]);
      float4 v0 = gp[j*2], v1 = gp[j*2 + 1];
      reinterpret_cast<float4*>(gbuf)[j*2]     = v0;
      reinterpret_cast<float4*>(gbuf)[j*2 + 1] = v1;
      __syncthreads();   // refill barrier
    }

    const int pv = spv[t];
    float cin = 0.f;
    if (j < DD){
      float hin;
      if (pv >= 0 && pv != t-1){
        hin = bf2f_(Hh16[pv*DD + j]);
        cin = preC;
      } else {                       // pv == -1 (carry) or pv == t-1 (live)
        hin = sh[j]; cin = sc[j];
      }
      xh[j] = hin;
    }
    __syncthreads();   // A

    // prefetch skip-c for t+1 (written at step spv[t+1] <= t-1 by SAME thread)
    float preC_n = 0.f;
    {
      int pvn = (t + 1 < TT) ? spv[t + 1] : -1;
      if (j < DD && pvn >= 0 && pvn < t)
        preC_n = Ch[(base + pvn)*DD + j];
    }

    // gates[j] = gbuf + h_in . Whh[j,:]
    {
      const float4* x4 = reinterpret_cast<const float4*>(xh);
      float a0=0.f,a1=0.f,a2=0.f,a3=0.f;
      #pragma unroll
      for (int i = 0; i < 32; i++){
        float4 xv = x4[i];
        a0 += xv.x*whh[4*i]; a1 += xv.y*whh[4*i+1]; a2 += xv.z*whh[4*i+2]; a3 += xv.w*whh[4*i+3];
      }
      sg[j] = gbuf[tc*512 + j] + (a0+a1)+(a2+a3);
    }
    __syncthreads();   // B

    if (j < DD){
      float ig = sg[j], fg = sg[DD + j], gg = sg[2*DD + j], og = sg[3*DD + j];
      float cn = sigmoidf_(fg)*cin + sigmoidf_(ig)*tanhf(gg);
      float hn = sigmoidf_(og)*tanhf(cn);
      sh[j] = hn; sc[j] = cn;
      Hh16[t*DD + j] = f2bf_(hn);
      Ch[(base + t)*DD + j] = cn;
      pred[j] = hn*pwv;
    }
    __syncthreads();   // C

    if (j < 64){
      float s = pred[j] + pred[j + 64];
      s += __shfl_down(s, 32); s += __shfl_down(s, 16); s += __shfl_down(s, 8);
      s += __shfl_down(s, 4);  s += __shfl_down(s, 2);  s += __shfl_down(s, 1);
      if (j == 0) out[base + t] = sigmoidf_(s + pbv);
    }
    preC = preC_n;
  }
}

// ---------------------------------------------------------------------------
// Launch.
// ---------------------------------------------------------------------------
extern "C" void kernel_launch(void* const* d_in, const int* in_sizes, int n_in,
                              void* d_out, int out_size, void* d_ws, size_t ws_size,
                              hipStream_t stream) {
  const int*   q     = (const int*)  d_in[0];
  const int*   r     = (const int*)  d_in[1];
  const float* k_emb = (const float*)d_in[2];
  const float* Mk    = (const float*)d_in[3];
  const float* Mv0   = (const float*)d_in[4];
  const float* f_W   = (const float*)d_in[5];
  const float* f_b   = (const float*)d_in[6];
  const float* a_W   = (const float*)d_in[7];
  const float* a_b   = (const float*)d_in[8];
  const float* e_W   = (const float*)d_in[9];
  const float* e_b   = (const float*)d_in[10];
  const float* add_W = (const float*)d_in[11];
  const float* add_b = (const float*)d_in[12];
  const float* Wih   = (const float*)d_in[13];
  const float* Whh   = (const float*)d_in[14];
  const float* bih   = (const float*)d_in[15];
  const float* bhh   = (const float*)d_in[16];
  const float* p_W   = (const float*)d_in[17];
  const float* p_b   = (const float*)d_in[18];
  float* out = (float*)d_out;

  char* ws = (char*)d_ws;
  size_t off = 0;
  auto alloc = [&](size_t bytes) -> char* {
    char* p = ws + off;
    off += (bytes + 255) & ~(size_t)255;
    return p;
  };
  float* wAll  = (float*)alloc((size_t)BB*TT*MM*4);
  float* fpre  = (float*)alloc((size_t)BB*TT*DD*4);
  float* ypre  = (float*)alloc((size_t)BB*TT*DD*4);
  float* fAll  = (float*)alloc((size_t)BB*TT*DD*4);
  float* gpre  = (float*)alloc((size_t)BB*TT*512*4);
  float* Ch    = (float*)alloc((size_t)BB*TT*DD*4);
  ull*   keyLo = (ull*)  alloc((size_t)BB*TT*8);
  ull*   keyHi = (ull*)  alloc((size_t)BB*TT*8);
  int*   prevA = (int*)  alloc((size_t)BB*TT*4);
  (void)ws_size; (void)in_sizes; (void)n_in; (void)out_size;

  kPre  <<<dim3(16, 32), 256, 0, stream>>>(q, r, k_emb, Mk, f_W, f_b, a_W, a_b,
                                           wAll, keyLo, keyHi, fpre, ypre);
  kMatch<<<32, 512, 0, stream>>>(keyLo, keyHi, prevA);
  kMem  <<<32, 512, 0, stream>>>(wAll, fpre, ypre, f_W, a_W, e_W, e_b, add_W, add_b,
                                 Mv0, fAll);
  kGate <<<dim3(8, 512), 256, 0, stream>>>(fAll, Wih, bih, bhh, gpre);
  kLstm <<<32, 512, 0, stream>>>(gpre, prevA, Whh, p_W, p_b, Ch, out);
}

// Round 4
// 1639.079 us; speedup vs baseline: 1.3898x; 1.3898x over previous
//
#include <hip/hip_runtime.h>
#include <cstdint>
#include <cstddef>

// Problem constants
#define NUM_C 4096
#define BB 32
#define TT 512
#define DD 128
#define MM 50

using ull = unsigned long long;

__device__ __forceinline__ float sigmoidf_(float x){ return 1.0f/(1.0f + expf(-x)); }

// Quad reduction via DPP (VALU pipe, no LDS): sum over lanes {x, x^1, x^2, x^3}
// quad_perm xor1 = [1,0,3,2] -> 0xB1 ; xor2 = [2,3,0,1] -> 0x4E
__device__ __forceinline__ float quadSum_(float v){
  int t = __builtin_amdgcn_update_dpp(0, __float_as_int(v), 0xB1, 0xF, 0xF, true);
  v += __int_as_float(t);
  t = __builtin_amdgcn_update_dpp(0, __float_as_int(v), 0x4E, 0xF, 0xF, true);
  v += __int_as_float(t);
  return v;
}

// ---------------------------------------------------------------------------
// Kernel A: parallel precompute (unchanged).
// ---------------------------------------------------------------------------
__global__ __launch_bounds__(256) void kPre(
    const int* __restrict__ q, const int* __restrict__ r,
    const float* __restrict__ k_emb, const float* __restrict__ Mk,
    const float* __restrict__ f_W, const float* __restrict__ f_b,
    const float* __restrict__ a_W, const float* __restrict__ a_b,
    float* __restrict__ wAll, ull* __restrict__ keyLo, ull* __restrict__ keyHi,
    float* __restrict__ fpre, float* __restrict__ ypre)
{
  const int b = blockIdx.y, t0 = blockIdx.x * 32, tid = threadIdx.x;
  __shared__ __align__(16) float sK[32*129];
  __shared__ int sQ[32];
  __shared__ int sR[32];
  __shared__ union UU {
    struct { float sMk[MM*129]; double sZ[32*MM]; } p2;
    float sW2[128*65];
  } u;

  if (tid < 32){ sQ[tid] = q[b*TT + t0 + tid]; sR[tid] = r[b*TT + t0 + tid]; }
  __syncthreads();
  for (int i = tid; i < 32*128; i += 256){
    int tl = i >> 7, j = i & 127;
    sK[tl*129 + j] = k_emb[(size_t)sQ[tl]*DD + j];
  }
  for (int i = tid; i < MM*128; i += 256){
    int m = i >> 7, j = i & 127;
    u.p2.sMk[m*129 + j] = Mk[i];
  }
  __syncthreads();

  for (int idx = tid; idx < 32*MM; idx += 256){
    int tl = idx / MM, m = idx - tl*MM;
    double z = 0.0;
    for (int j = 0; j < DD; j++)
      z += (double)sK[tl*129 + j] * (double)u.p2.sMk[m*129 + j];
    u.p2.sZ[tl*MM + m] = z;
  }
  __syncthreads();

  {
    int tl = tid >> 3, l8 = tid & 7;
    double zmax = -1e300;
    for (int m = l8; m < MM; m += 8) zmax = fmax(zmax, u.p2.sZ[tl*MM + m]);
    for (int s = 1; s < 8; s <<= 1) zmax = fmax(zmax, __shfl_xor(zmax, s));
    double se = 0.0;
    for (int m = l8; m < MM; m += 8){
      double e = exp(u.p2.sZ[tl*MM + m] - zmax);
      u.p2.sZ[tl*MM + m] = e;
      se += e;
    }
    for (int s = 1; s < 8; s <<= 1) se += __shfl_xor(se, s);
    double inv = 1.0 / se;
    ull klo = 0, khi = 0;
    for (int m = l8; m < MM; m += 8){
      double w = u.p2.sZ[tl*MM + m] * inv;
      wAll[((size_t)(b*TT + t0 + tl))*MM + m] = (float)w;
      double tw = fmin((w - 0.075)/(0.088 - 0.075), (1.0 - w)/(1.0 - 0.088));
      tw = fmax(tw, 0.0);
      ull iv = (tw >= 0.6) ? 2ull : ((tw >= 0.1) ? 1ull : 0ull);
      if (m < 32) klo |= iv << (2*m); else khi |= iv << (2*(m-32));
    }
    for (int s = 1; s < 8; s <<= 1){ klo |= __shfl_xor(klo, s); khi |= __shfl_xor(khi, s); }
    if (l8 == 0){ keyLo[b*TT + t0 + tl] = klo; keyHi[b*TT + t0 + tl] = khi; }
  }

  {
    const int dq = tid & 31, tq = tid >> 5;
    float acc[4][4];
    #pragma unroll
    for (int a = 0; a < 4; a++){ acc[a][0]=0.f; acc[a][1]=0.f; acc[a][2]=0.f; acc[a][3]=0.f; }
    for (int jh = 0; jh < 2; jh++){
      __syncthreads();
      for (int i = tid; i < 128*64; i += 256){
        int dd = i >> 6, jj = i & 63;
        u.sW2[dd*65 + jj] = f_W[dd*256 + 128 + jh*64 + jj];
      }
      __syncthreads();
      for (int jj = 0; jj < 64; jj++){
        float kv[4], wv[4];
        #pragma unroll
        for (int a = 0; a < 4; a++) kv[a] = sK[(tq*4 + a)*129 + jh*64 + jj];
        #pragma unroll
        for (int c = 0; c < 4; c++) wv[c] = u.sW2[(dq*4 + c)*65 + jj];
        #pragma unroll
        for (int a = 0; a < 4; a++){
          acc[a][0] += kv[a]*wv[0]; acc[a][1] += kv[a]*wv[1];
          acc[a][2] += kv[a]*wv[2]; acc[a][3] += kv[a]*wv[3];
        }
      }
    }
    #pragma unroll
    for (int a = 0; a < 4; a++){
      int tl = tq*4 + a;
      #pragma unroll
      for (int c = 0; c < 4; c++){
        int d = dq*4 + c;
        fpre[((size_t)(b*TT + t0 + tl))*DD + d] = acc[a][c] + f_b[d];
      }
    }
  }

  for (int i = tid; i < 32*DD; i += 256){
    int tl = i >> 7, d = i & 127;
    ypre[((size_t)(b*TT + t0 + tl))*DD + d] =
        a_W[(size_t)d*(NUM_C + DD) + sQ[tl]] * (float)sR[tl] + a_b[d];
  }
}

// ---------------------------------------------------------------------------
// Kernel A2: exact match search (unchanged).
// ---------------------------------------------------------------------------
__global__ __launch_bounds__(512) void kMatch(
    const ull* __restrict__ keyLo, const ull* __restrict__ keyHi, int* __restrict__ prevA)
{
  const int b = blockIdx.x, i = threadIdx.x;
  __shared__ ull slo[TT];
  __shared__ ull shi[TT];
  slo[i] = keyLo[b*TT + i];
  shi[i] = keyHi[b*TT + i];
  __syncthreads();
  const ull mylo = slo[i], myhi = shi[i];
  int found = -1;
  for (int j = i - 1; j >= 0; j--){
    if (slo[j] == mylo && shi[j] == myhi){ found = j; break; }
  }
  prevA[b*TT + i] = found;
}

// ---------------------------------------------------------------------------
// Kernel B (R4): memory recurrence. Quad mapping (do = tid>>2, kc = tid&3):
// reductions over kc are DPP quad-adds on the VALU pipe (no LDS shuffles).
// Chunk-staged wAll/fpre/ypre; fAll buffered and flushed per 8-step chunk.
// ---------------------------------------------------------------------------
__global__ __launch_bounds__(512, 2) void kMem(
    const float* __restrict__ wAll, const float* __restrict__ fpre, const float* __restrict__ ypre,
    const float* __restrict__ f_W, const float* __restrict__ a_W,
    const float* __restrict__ e_W, const float* __restrict__ e_b,
    const float* __restrict__ add_W, const float* __restrict__ add_b,
    const float* __restrict__ Mv0, float* __restrict__ fAll)
{
  const int b = blockIdx.x, tid = threadIdx.x;
  const int dd = tid >> 2;               // output index 0..127
  const int kc = tid & 3;                // quad lane: K-slice / m-slice selector
  const int m0 = kc*13;                  // m-chunk base (13,13,13,11)
  const int wslot = (dd >> 5)*36 + (dd & 31);   // padded write position

  // register-resident state & weights
  float mv[13];
  #pragma unroll
  for (int i = 0; i < 13; i++){
    int m = m0 + i;
    mv[i] = (m < MM) ? Mv0[(size_t)m*DD + dd] : 0.f;
  }
  float wf[32], wa[32], we[32], wd[32];
  {
    const float4* p;
    p = reinterpret_cast<const float4*>(&f_W[dd*256 + kc*32]);
    #pragma unroll
    for (int i = 0; i < 8; i++){ float4 v = p[i]; wf[4*i]=v.x; wf[4*i+1]=v.y; wf[4*i+2]=v.z; wf[4*i+3]=v.w; }
    p = reinterpret_cast<const float4*>(&a_W[(size_t)dd*(NUM_C + DD) + NUM_C + kc*32]);
    #pragma unroll
    for (int i = 0; i < 8; i++){ float4 v = p[i]; wa[4*i]=v.x; wa[4*i+1]=v.y; wa[4*i+2]=v.z; wa[4*i+3]=v.w; }
    p = reinterpret_cast<const float4*>(&e_W[dd*DD + kc*32]);
    #pragma unroll
    for (int i = 0; i < 8; i++){ float4 v = p[i]; we[4*i]=v.x; we[4*i+1]=v.y; we[4*i+2]=v.z; we[4*i+3]=v.w; }
    p = reinterpret_cast<const float4*>(&add_W[dd*DD + kc*32]);
    #pragma unroll
    for (int i = 0; i < 8; i++){ float4 v = p[i]; wd[4*i]=v.x; wd[4*i+1]=v.y; wd[4*i+2]=v.z; wd[4*i+3]=v.w; }
  }
  const float ebv = e_b[dd], adbv = add_b[dd];

  __shared__ __align__(16) float bufR[144];
  __shared__ __align__(16) float bufF[144];
  __shared__ __align__(16) float bufY[144];
  __shared__ float sW8[8*52];
  __shared__ __align__(16) float sF8[8*128];
  __shared__ __align__(16) float sY8[8*128];
  __shared__ __align__(16) float fO8[8*128];

  const size_t base = (size_t)b*TT;

  for (int t = 0; t < TT; t++){
    const int tc = t & 7;
    if (tc == 0){
      if (t){
        if (tid < 256){
          const float4* s4 = reinterpret_cast<const float4*>(fO8);
          float4 v = s4[tid];
          reinterpret_cast<float4*>(&fAll[(base + t - 8)*DD])[tid] = v;
        }
      }
      if (tid < 256){
        float4 v = reinterpret_cast<const float4*>(&fpre[(base + t)*DD])[tid];
        reinterpret_cast<float4*>(sF8)[tid] = v;
      } else {
        float4 v = reinterpret_cast<const float4*>(&ypre[(base + t)*DD])[tid - 256];
        reinterpret_cast<float4*>(sY8)[tid - 256] = v;
      }
      if (tid < 400){
        int rr = tid / MM, mm = tid - rr*MM;
        sW8[rr*52 + mm] = wAll[(base + t + rr)*MM + mm];
      }
      __syncthreads();   // R
    }

    float wcur[13];
    #pragma unroll
    for (int i = 0; i < 13; i++)
      wcur[i] = (m0 + i < MM) ? sW8[tc*52 + m0 + i] : 0.f;

    // ---- stage 1: read[dd] partial over own m-slice; quad reduce ----
    {
      float a0 = 0.f;
      #pragma unroll
      for (int i = 0; i < 13; i++) a0 += wcur[i]*mv[i];
      a0 = quadSum_(a0);
      if (kc == 0) bufR[wslot] = a0;
    }
    __syncthreads();   // A

    // ---- stage 2: f = tanh(read @ f_Wr.T + fpre) ----
    {
      const float4* x4 = reinterpret_cast<const float4*>(&bufR[kc*36]);
      float a0=0.f,a1=0.f,a2=0.f,a3=0.f;
      #pragma unroll
      for (int i = 0; i < 8; i++){
        float4 xv = x4[i];
        a0 += xv.x*wf[4*i]; a1 += xv.y*wf[4*i+1]; a2 += xv.z*wf[4*i+2]; a3 += xv.w*wf[4*i+3];
      }
      float s = quadSum_((a0+a1)+(a2+a3));
      float fval = tanhf(s + sF8[tc*128 + dd]);
      if (kc == 0){
        bufF[wslot] = fval;
        fO8[tc*128 + dd] = fval;
      }
    }
    __syncthreads();   // B

    // ---- stage 3: y = ypre + f @ a_Wf.T ----
    {
      const float4* x4 = reinterpret_cast<const float4*>(&bufF[kc*36]);
      float a0=0.f,a1=0.f,a2=0.f,a3=0.f;
      #pragma unroll
      for (int i = 0; i < 8; i++){
        float4 xv = x4[i];
        a0 += xv.x*wa[4*i]; a1 += xv.y*wa[4*i+1]; a2 += xv.z*wa[4*i+2]; a3 += xv.w*wa[4*i+3];
      }
      float s = quadSum_((a0+a1)+(a2+a3));
      if (kc == 0) bufY[wslot] = s + sY8[tc*128 + dd];
    }
    __syncthreads();   // C

    // ---- stage 4: e,a + Mv register update (no barrier) ----
    {
      const float4* x4 = reinterpret_cast<const float4*>(&bufY[kc*36]);
      float e0=0.f,e1=0.f,g0=0.f,g1=0.f;
      #pragma unroll
      for (int i = 0; i < 8; i++){
        float4 xv = x4[i];
        e0 += xv.x*we[4*i];   e1 += xv.y*we[4*i+1];
        e0 += xv.z*we[4*i+2]; e1 += xv.w*we[4*i+3];
        g0 += xv.x*wd[4*i];   g1 += xv.y*wd[4*i+1];
        g0 += xv.z*wd[4*i+2]; g1 += xv.w*wd[4*i+3];
      }
      float ep = quadSum_(e0 + e1);
      float ap = quadSum_(g0 + g1);
      float e_d = sigmoidf_(ep + ebv);
      float a_d = tanhf(ap + adbv);
      #pragma unroll
      for (int i = 0; i < 13; i++){
        float wv = wcur[i];
        mv[i] = mv[i]*(1.f - wv*e_d) + wv*a_d;
      }
    }
  }

  __syncthreads();
  if (tid < 256){
    const float4* s4 = reinterpret_cast<const float4*>(fO8);
    float4 v = s4[tid];
    reinterpret_cast<float4*>(&fAll[(base + TT - 8)*DD])[tid] = v;
  }
}

// ---------------------------------------------------------------------------
// Kernel D: gpre GEMM (unchanged).
// ---------------------------------------------------------------------------
__global__ __launch_bounds__(256) void kGate(
    const float* __restrict__ fAll, const float* __restrict__ Wih,
    const float* __restrict__ bih, const float* __restrict__ bhh,
    float* __restrict__ gpre)
{
  const int jt = blockIdx.x;
  const int rt = blockIdx.y;
  const int tid = threadIdx.x;
  __shared__ float sW[64*129];
  __shared__ float sF[32*129];
  for (int i = tid; i < 64*128; i += 256){
    int jj = i >> 7, k = i & 127;
    sW[jj*129 + k] = Wih[(size_t)(jt*64 + jj)*128 + k];
  }
  for (int i = tid; i < 32*128; i += 256){
    int rr = i >> 7, k = i & 127;
    sF[rr*129 + k] = fAll[(size_t)(rt*32 + rr)*128 + k];
  }
  __syncthreads();
  const int jq = tid & 31, rq = tid >> 5;
  float acc[4][2];
  #pragma unroll
  for (int a = 0; a < 4; a++){ acc[a][0] = 0.f; acc[a][1] = 0.f; }
  for (int k = 0; k < 128; k++){
    float fv[4], wv[2];
    #pragma unroll
    for (int a = 0; a < 4; a++) fv[a] = sF[(rq*4 + a)*129 + k];
    wv[0] = sW[(jq*2 + 0)*129 + k];
    wv[1] = sW[(jq*2 + 1)*129 + k];
    #pragma unroll
    for (int a = 0; a < 4; a++){ acc[a][0] += fv[a]*wv[0]; acc[a][1] += fv[a]*wv[1]; }
  }
  #pragma unroll
  for (int a = 0; a < 4; a++){
    int rowi = rt*32 + rq*4 + a;
    #pragma unroll
    for (int c = 0; c < 2; c++){
      int j = jt*64 + jq*2 + c;
      gpre[(size_t)rowi*512 + j] = acc[a][c] + bih[j] + bhh[j];
    }
  }
}

// ---------------------------------------------------------------------------
// Kernel C (R4): LSTM, quad-mapped. Thread (jo = tid>>2, kc = tid&3) owns
// all 4 gates of cell jo over K-slice kc*32..+32. DPP quad reduce -> cell
// update in-register (no sg LDS, no extra barriers). Carry h/c and skip
// H/C (global fp32, prefetched early-step) in registers. h broadcast via
// double-buffered padded xh. gpre relayed global->reg->LDS per 8 steps.
// ONE barrier per step (two on chunk boundaries). Output head moved to kOut.
// ---------------------------------------------------------------------------
__global__ __launch_bounds__(512, 2) void kLstm(
    const float* __restrict__ gpre, const int* __restrict__ prevA,
    const float* __restrict__ Whh,
    float* __restrict__ Hh, float* __restrict__ Ch)
{
  const int b = blockIdx.x, tid = threadIdx.x;
  const int jo = tid >> 2, kc = tid & 3;
  const int wslot = (jo >> 5)*36 + (jo & 31);

  // Whh rows for the 4 gates of cell jo, K-slice kc*32..+32 (128 floats)
  float whh[4][32];
  #pragma unroll
  for (int g = 0; g < 4; g++){
    const float4* W4 = reinterpret_cast<const float4*>(&Whh[(size_t)(g*128 + jo)*128 + kc*32]);
    #pragma unroll
    for (int i = 0; i < 8; i++){
      float4 v = W4[i];
      whh[g][4*i] = v.x; whh[g][4*i+1] = v.y; whh[g][4*i+2] = v.z; whh[g][4*i+3] = v.w;
    }
  }

  __shared__ __align__(16) float xh[2][144];      // padded h_in broadcast (double buffer)
  __shared__ __align__(16) float gbuf[2][8*512];  // 32 KB gpre chunks
  __shared__ int spv[TT];

  const size_t base = (size_t)b*TT;
  float4 gr0, gr1;
  {
    const float4* g0 = reinterpret_cast<const float4*>(&gpre[base*512]);
    float4 a = g0[tid*2], c = g0[tid*2+1];
    float4* gb4 = reinterpret_cast<float4*>(gbuf[0]);
    gb4[tid*2] = a; gb4[tid*2+1] = c;
    const float4* g1 = reinterpret_cast<const float4*>(&gpre[(base + 8)*512]);
    gr0 = g1[tid*2]; gr1 = g1[tid*2+1];
    spv[tid] = prevA[base + tid];
    if (tid < DD) xh[0][(tid >> 5)*36 + (tid & 31)] = 0.f;
  }
  __syncthreads();

  float cin_cur = 0.f;   // c_in for current step (selected at end of prev step)

  for (int t = 0; t < TT; t++){
    const int tc = t & 7, p = t & 1, pc = (t >> 3) & 1;
    if (tc == 0 && t){
      __syncthreads();   // prior step's xh writes + old gbuf reads done
      float4* gb4 = reinterpret_cast<float4*>(gbuf[pc]);
      gb4[tid*2] = gr0; gb4[tid*2+1] = gr1;
      if (t + 8 < TT){
        const float4* gp4 = reinterpret_cast<const float4*>(&gpre[(base + t + 8)*512]);
        gr0 = gp4[tid*2]; gr1 = gp4[tid*2+1];
      }
      __syncthreads();   // publish chunk
    } else if (t) {
      __syncthreads();   // xh[p] ready
    }

    const size_t row = base + t;

    // early prefetch of skip state for t+1 (consumed at end of this step)
    int pv2 = -1; float preH = 0.f, preC = 0.f;
    if (t + 1 < TT){
      pv2 = spv[t + 1];
      if (pv2 >= 0 && pv2 < t){
        preH = Hh[(base + pv2)*DD + jo];
        preC = Ch[(base + pv2)*DD + jo];
      }
    }

    // gate pre-activations
    float gp0 = gbuf[pc][tc*512 + jo];
    float gp1 = gbuf[pc][tc*512 + 128 + jo];
    float gp2 = gbuf[pc][tc*512 + 256 + jo];
    float gp3 = gbuf[pc][tc*512 + 384 + jo];

    // gates matvec over K-slice
    float a0=0.f,a1=0.f,a2=0.f,a3=0.f;
    {
      const float4* x4 = reinterpret_cast<const float4*>(&xh[p][kc*36]);
      #pragma unroll
      for (int i = 0; i < 8; i++){
        float4 xv = x4[i];
        a0 += xv.x*whh[0][4*i]; a0 += xv.y*whh[0][4*i+1]; a0 += xv.z*whh[0][4*i+2]; a0 += xv.w*whh[0][4*i+3];
        a1 += xv.x*whh[1][4*i]; a1 += xv.y*whh[1][4*i+1]; a1 += xv.z*whh[1][4*i+2]; a1 += xv.w*whh[1][4*i+3];
        a2 += xv.x*whh[2][4*i]; a2 += xv.y*whh[2][4*i+1]; a2 += xv.z*whh[2][4*i+2]; a2 += xv.w*whh[2][4*i+3];
        a3 += xv.x*whh[3][4*i]; a3 += xv.y*whh[3][4*i+1]; a3 += xv.z*whh[3][4*i+2]; a3 += xv.w*whh[3][4*i+3];
      }
    }
    a0 = quadSum_(a0); a1 = quadSum_(a1); a2 = quadSum_(a2); a3 = quadSum_(a3);

    const float ig = gp0 + a0, fg = gp1 + a1, gg = gp2 + a2, og = gp3 + a3;
    const float cn = sigmoidf_(fg)*cin_cur + sigmoidf_(ig)*tanhf(gg);
    const float hn = sigmoidf_(og)*tanhf(cn);

    if (kc == 0){
      Hh[row*DD + jo] = hn;
      Ch[row*DD + jo] = cn;
    }

    // select inputs for t+1, publish h_in to the other xh buffer
    float hin_n, cin_n;
    if (pv2 < 0 || pv2 >= t){ hin_n = hn; cin_n = cn; }       // carry (pv2==-1 or pv2==t)
    else                     { hin_n = preH; cin_n = preC; }   // skip (prefetched)
    if (kc == 0) xh[1 - p][wslot] = hin_n;
    cin_cur = cin_n;
  }
}

// ---------------------------------------------------------------------------
// Kernel E: output head (parallel): out[row] = sigmoid(h . p_W + p_b).
// 16 lanes per row, 16 rows per 256-thread block.
// ---------------------------------------------------------------------------
__global__ __launch_bounds__(256) void kOut(
    const float* __restrict__ Hh, const float* __restrict__ p_W,
    const float* __restrict__ p_b, float* __restrict__ out)
{
  const int row = blockIdx.x*16 + (threadIdx.x >> 4);
  const int l = threadIdx.x & 15;
  const float4* h4 = reinterpret_cast<const float4*>(&Hh[(size_t)row*DD + l*8]);
  const float4* w4 = reinterpret_cast<const float4*>(&p_W[l*8]);
  float4 ha = h4[0], hb = h4[1], wa = w4[0], wb = w4[1];
  float s = ha.x*wa.x + ha.y*wa.y + ha.z*wa.z + ha.w*wa.w
          + hb.x*wb.x + hb.y*wb.y + hb.z*wb.z + hb.w*wb.w;
  s += __shfl_xor(s, 1); s += __shfl_xor(s, 2);
  s += __shfl_xor(s, 4); s += __shfl_xor(s, 8);
  if (l == 0) out[row] = sigmoidf_(s + p_b[0]);
}

// ---------------------------------------------------------------------------
// Launch.
// ---------------------------------------------------------------------------
extern "C" void kernel_launch(void* const* d_in, const int* in_sizes, int n_in,
                              void* d_out, int out_size, void* d_ws, size_t ws_size,
                              hipStream_t stream) {
  const int*   q     = (const int*)  d_in[0];
  const int*   r     = (const int*)  d_in[1];
  const float* k_emb = (const float*)d_in[2];
  const float* Mk    = (const float*)d_in[3];
  const float* Mv0   = (const float*)d_in[4];
  const float* f_W   = (const float*)d_in[5];
  const float* f_b   = (const float*)d_in[6];
  const float* a_W   = (const float*)d_in[7];
  const float* a_b   = (const float*)d_in[8];
  const float* e_W   = (const float*)d_in[9];
  const float* e_b   = (const float*)d_in[10];
  const float* add_W = (const float*)d_in[11];
  const float* add_b = (const float*)d_in[12];
  const float* Wih   = (const float*)d_in[13];
  const float* Whh   = (const float*)d_in[14];
  const float* bih   = (const float*)d_in[15];
  const float* bhh   = (const float*)d_in[16];
  const float* p_W   = (const float*)d_in[17];
  const float* p_b   = (const float*)d_in[18];
  float* out = (float*)d_out;

  char* ws = (char*)d_ws;
  size_t off = 0;
  auto alloc = [&](size_t bytes) -> char* {
    char* p = ws + off;
    off += (bytes + 255) & ~(size_t)255;
    return p;
  };
  float* wAll  = (float*)alloc((size_t)BB*TT*MM*4);
  float* fpre  = (float*)alloc((size_t)BB*TT*DD*4);
  float* ypre  = (float*)alloc((size_t)BB*TT*DD*4);
  float* fAll  = (float*)alloc((size_t)BB*TT*DD*4);
  float* gpre  = (float*)alloc((size_t)BB*TT*512*4);
  float* Hh    = (float*)alloc((size_t)BB*TT*DD*4);
  float* Ch    = (float*)alloc((size_t)BB*TT*DD*4);
  ull*   keyLo = (ull*)  alloc((size_t)BB*TT*8);
  ull*   keyHi = (ull*)  alloc((size_t)BB*TT*8);
  int*   prevA = (int*)  alloc((size_t)BB*TT*4);
  (void)ws_size; (void)in_sizes; (void)n_in; (void)out_size;

  kPre  <<<dim3(16, 32), 256, 0, stream>>>(q, r, k_emb, Mk, f_W, f_b, a_W, a_b,
                                           wAll, keyLo, keyHi, fpre, ypre);
  kMatch<<<32, 512, 0, stream>>>(keyLo, keyHi, prevA);
  kMem  <<<32, 512, 0, stream>>>(wAll, fpre, ypre, f_W, a_W, e_W, e_b, add_W, add_b,
                                 Mv0, fAll);
  kGate <<<dim3(8, 512), 256, 0, stream>>>(fAll, Wih, bih, bhh, gpre);
  kLstm <<<32, 512, 0, stream>>>(gpre, prevA, Whh, Hh, Ch);
  kOut  <<<(BB*TT)/16, 256, 0, stream>>>(Hh, p_W, p_b, out);
}